// Round 3
// baseline (696.770 us; speedup 1.0000x reference)
//
#include <hip/hip_runtime.h>
#include <hip/hip_bf16.h>
#include <stdint.h>

// Problem constants (reference: N=4096, D=1024, V=50257)
#define NROWS 4096
#define DDIM  1024
#define VDIM  50257
#define VPAD  50304   // 393 * 128
#define NVT   393     // v-tiles
#define NMT   16      // m-tiles (256 rows each)

// fp8 scales: w*64, x*8 -> logits scaled by 512 (exact pow2, descale pre-exp)
#define DESCALE (1.0f / 512.0f)

// LDS stage: A 256 rows + B 128 rows, 64B data/row (fp8 K=64), pitch 80.
// Rows are PLAIN k-order (x64 scaled MFMA: lane half h = l>>5 reads the
// contiguous bytes k = h*32 .. h*32+31 of the 64-k stage: two b128 at
// h*32 + {0,16}). Pitch 80 (5 x 16B units, gcd(5,8)=1) keeps the b128 frag
// reads conflict-free per 8-lane phase (5c mod 8 is a bijection on 0..7).
// Layout verified correct on HW (rounds 1-2 absmax 0.0).
#define PITCH  80
#define B_BASE 20480             // 256*80
#define STAGE  30720             // + 128*80

typedef long  i64;
typedef i64   i64x2 __attribute__((ext_vector_type(2)));
typedef int   i32x4 __attribute__((ext_vector_type(4)));
typedef int   i32x8 __attribute__((ext_vector_type(8)));
typedef float f32x16 __attribute__((ext_vector_type(16)));

// e8m0 1.0 scales (exponent 127 -> 2^0): numerically exact, keeps absmax 0.
#define SCALE1 0x7F7F7F7F

// Two ds_read_b128 -> one 8-VGPR MFMA operand, built AT the use site so the
// aligned octet's live range is minimal (round-1 spilled to scratch by
// keeping six octets live across the staging phase).
__device__ __forceinline__ i32x8 ld_frag(const unsigned char* p) {
  i32x4 lo = *(const i32x4*)p;
  i32x4 hi = *(const i32x4*)(p + 16);
  return __builtin_shufflevector(lo, hi, 0, 1, 2, 3, 4, 5, 6, 7);
}

// Raw barrier that drains ONLY lgkmcnt (LDS visibility needs it); global
// loads stay in flight across the barrier (T4 counted-vmcnt: the compiler
// emits counted vmcnt(N) before the ds_writes that consume them next iter).
// asm memory clobbers pin all LDS ops on their side of the barrier.
__device__ __forceinline__ void lds_barrier() {
  asm volatile("s_waitcnt lgkmcnt(0)" ::: "memory");
  __builtin_amdgcn_s_barrier();
  asm volatile("" ::: "memory");
}

// ---- fp32 -> fp8 e4m3 (OCP on gfx950), 16 elems/thread, scaled; zero pad ----
__global__ __launch_bounds__(256)
void cvtq_kernel(const float* __restrict__ src, uint32_t* __restrict__ dst,
                 size_t n_src, float scale) {
  size_t i = ((size_t)blockIdx.x * 256 + threadIdx.x) * 16;
  uint32_t o[4] = {0u, 0u, 0u, 0u};
  if (i < n_src) {   // n_src is a multiple of 16 -> all-or-nothing is exact
    const float4* s = (const float4*)(src + i);
    #pragma unroll
    for (int d = 0; d < 4; ++d) {
      float4 f = s[d];
      uint32_t v = 0;
      v = __builtin_amdgcn_cvt_pk_fp8_f32(f.x * scale, f.y * scale, v, false);
      v = __builtin_amdgcn_cvt_pk_fp8_f32(f.z * scale, f.w * scale, v, true);
      o[d] = v;
    }
  }
  *(uint4*)(dst + i / 4) = make_uint4(o[0], o[1], o[2], o[3]);
}

// ---- exact fp32 target logit: lt[n] = dot(x[n], w[target[n]]) ----
__global__ __launch_bounds__(256)
void tlogit_kernel(const float* __restrict__ x, const float* __restrict__ w,
                   const int* __restrict__ tgt, float* __restrict__ lt) {
  int n = blockIdx.x;
  int t = tgt[n];
  const float4* xr = (const float4*)(x + (size_t)n * DDIM);
  const float4* wr = (const float4*)(w + (size_t)t * DDIM);
  float4 a = xr[threadIdx.x];
  float4 b = wr[threadIdx.x];
  float s = a.x * b.x + a.y * b.y + a.z * b.z + a.w * b.w;
  #pragma unroll
  for (int m = 32; m; m >>= 1) s += __shfl_down(s, m);
  __shared__ float red[4];
  if ((threadIdx.x & 63) == 0) red[threadIdx.x >> 6] = s;
  __syncthreads();
  if (threadIdx.x == 0) lt[n] = red[0] + red[1] + red[2] + red[3];
}

// ---- fused fp8 GEMM (scaled 32x32x64 f8f6f4, unit scales) + exp + row-sum ----
// Block 256x128xBK64, 4 waves (2m x 2n), wave tile 128x64. Reg-staged
// distance-2 pipeline with NON-DRAINING barrier: per K-iter the staging phase
// (ds_write k+1, issue global loads k+2) runs first, then frag reads
// interleaved per-mi with the 8 scaled MFMAs; the end-of-iter barrier drains
// lgkmcnt only, so the k+2 loads stay in flight across it (counted vmcnt).
// XCD swizzle: the 16 m-tiles of one v-slab share flat&7 -> one XCD streams
// each weight slab once; fp8 A (4MB) becomes L2-resident per XCD.
__global__ __launch_bounds__(256, 2)
void gemm_lse_kernel(const uint8_t* __restrict__ xq,   // [NROWS][DDIM] fp8
                     const uint8_t* __restrict__ wq,   // [VPAD][DDIM] fp8 (pad 0)
                     float* __restrict__ S) {          // [NROWS] sum of exp
  __shared__ __align__(16) unsigned char smem[2 * STAGE];  // 60 KB

  const int tid  = threadIdx.x;
  const int wid  = tid >> 6;    // 0..3
  const int lane = tid & 63;
  const int c31  = lane & 31;
  const int h    = lane >> 5;   // 0..1

  // Block remap: grid (16,393) -> flat; same-v blocks share flat&7 (same XCD
  // under id%8 round-robin). Tail 16 blocks -> v-tile 392.
  const int flat = blockIdx.x + blockIdx.y * 16;
  int bm, vt;
  if (flat >= (NVT - 1) * 16) { vt = NVT - 1; bm = flat - (NVT - 1) * 16; }
  else { vt = (flat >> 7) * 8 + (flat & 7); bm = (flat >> 3) & 15; }
  const int m0 = bm * 256;
  const int v0 = vt * 128;

  const int wave_m = wid >> 1;  // 0..1
  const int wave_n = wid & 1;   // 0..1

  // Staging: per inst 16 rows x 64B contiguous (lane -> row lane>>2, 16B piece
  // lane&3). Plain k-order: piece lc lands at byte lc*16 (one b128 write).
  const int lr = lane >> 2;   // 0..15
  const int lc = lane & 3;    // 0..3
  const uint8_t* gA[4]; uint32_t wAo[4];
  #pragma unroll
  for (int a = 0; a < 4; ++a) {
    int r = (wid * 4 + a) * 16 + lr;                 // 0..255
    gA[a]  = xq + (size_t)(m0 + r) * DDIM + lc * 16;
    wAo[a] = (uint32_t)(r * PITCH + lc * 16);
  }
  const uint8_t* gB[2]; uint32_t wBo[2];
  #pragma unroll
  for (int b = 0; b < 2; ++b) {
    int r = (wid * 2 + b) * 16 + lr;                 // 0..127
    gB[b]  = wq + (size_t)(v0 + r) * DDIM + lc * 16;
    wBo[b] = (uint32_t)(B_BASE + r * PITCH + lc * 16);
  }

  // Fragment read offsets: row m, k-half h -> bytes h*32 + {0,16}.
  uint32_t aoff[4], boff[2];
  #pragma unroll
  for (int mi = 0; mi < 4; ++mi)
    aoff[mi] = (uint32_t)((wave_m * 128 + mi * 32 + c31) * PITCH + h * 32);
  #pragma unroll
  for (int ni = 0; ni < 2; ++ni)
    boff[ni] = (uint32_t)(B_BASE + (wave_n * 64 + ni * 32 + c31) * PITCH + h * 32);

  f32x16 acc[4][2] = {};
  i64x2 rA[4], rB[2];

  // Prologue: load+write stage 0, issue stage 1 loads.
  #pragma unroll
  for (int a = 0; a < 4; ++a) rA[a] = *(const i64x2*)gA[a];
  #pragma unroll
  for (int b = 0; b < 2; ++b) rB[b] = *(const i64x2*)gB[b];
  #pragma unroll
  for (int a = 0; a < 4; ++a) *(i64x2*)(smem + wAo[a]) = rA[a];
  #pragma unroll
  for (int b = 0; b < 2; ++b) *(i64x2*)(smem + wBo[b]) = rB[b];
  #pragma unroll
  for (int a = 0; a < 4; ++a) rA[a] = *(const i64x2*)(gA[a] + 64);
  #pragma unroll
  for (int b = 0; b < 2; ++b) rB[b] = *(const i64x2*)(gB[b] + 64);
  lds_barrier();

  #pragma unroll 2
  for (int k = 0; k < 16; ++k) {
    const uint32_t sb = (uint32_t)(k & 1) * STAGE;
    const uint32_t nb = STAGE - sb;

    // --- staging phase: write stage k+1 (safe: other buffer; prior-iter
    // barrier ordered all reads of it; compiler inserts counted vmcnt for
    // rA/rB), then issue stage k+2 global loads (WAR on rA/rB is safe:
    // in-order issue reads ds_write sources before the load rewrites them) ---
    if (k + 1 < 16) {
      #pragma unroll
      for (int a = 0; a < 4; ++a) *(i64x2*)(smem + nb + wAo[a]) = rA[a];
      #pragma unroll
      for (int b = 0; b < 2; ++b) *(i64x2*)(smem + nb + wBo[b]) = rB[b];
    }
    if (k + 2 < 16) {
      #pragma unroll
      for (int a = 0; a < 4; ++a) rA[a] = *(const i64x2*)(gA[a] + (k + 2) * 64);
      #pragma unroll
      for (int b = 0; b < 2; ++b) rB[b] = *(const i64x2*)(gB[b] + (k + 2) * 64);
    }

    __builtin_amdgcn_sched_barrier(0);  // frag reads must NOT hoist above

    // --- compute phase: per-mi frag read feeding 2 MFMAs; at most ~4
    // operand octets live at once, none across the staging phase ---
    i32x8 bf0 = ld_frag(smem + sb + boff[0]);
    i32x8 bf1 = ld_frag(smem + sb + boff[1]);
    #pragma unroll
    for (int mi = 0; mi < 4; ++mi) {
      i32x8 afm = ld_frag(smem + sb + aoff[mi]);
      acc[mi][0] = __builtin_amdgcn_mfma_scale_f32_32x32x64_f8f6f4(
          afm, bf0, acc[mi][0], 0, 0, 0, SCALE1, 0, SCALE1);
      acc[mi][1] = __builtin_amdgcn_mfma_scale_f32_32x32x64_f8f6f4(
          afm, bf1, acc[mi][1], 0, 0, 0, SCALE1, 0, SCALE1);
    }

    __builtin_amdgcn_sched_barrier(0);  // keep MFMA cluster above the barrier
    // Non-draining barrier: lgkmcnt(0) only; k+2 loads stay in flight.
    lds_barrier();
  }

  // Epilogue: descale, exp, row-sum. 32x32 C/D: col = lane&31,
  // row = (reg&3) + 8*(reg>>2) + 4*(lane>>5).
  #pragma unroll
  for (int mi = 0; mi < 4; ++mi) {
    #pragma unroll
    for (int r = 0; r < 16; ++r) {
      float pacc = 0.f;
      #pragma unroll
      for (int ni = 0; ni < 2; ++ni) {
        int v = v0 + wave_n * 64 + ni * 32 + c31;
        float e = __expf(acc[mi][ni][r] * DESCALE);
        pacc += (v < VDIM) ? e : 0.f;   // mask vocab pad
      }
      pacc += __shfl_xor(pacc, 16);
      pacc += __shfl_xor(pacc, 8);
      pacc += __shfl_xor(pacc, 4);
      pacc += __shfl_xor(pacc, 2);
      pacc += __shfl_xor(pacc, 1);
      if (c31 == 0) {
        int row = m0 + wave_m * 128 + mi * 32 + (r & 3) + 8 * (r >> 2) + 4 * h;
        atomicAdd(&S[row], pacc);
      }
    }
  }
}

// ---- final: loss = mean(log(S[n]) - lt[n]) ----
__global__ __launch_bounds__(1024)
void loss_kernel(const float* __restrict__ S, const float* __restrict__ lt,
                 float* __restrict__ out) {
  float s = 0.f;
  for (int n = threadIdx.x; n < NROWS; n += 1024)
    s += logf(S[n]) - lt[n];
  #pragma unroll
  for (int m = 32; m; m >>= 1) s += __shfl_down(s, m);
  __shared__ float red[16];
  if ((threadIdx.x & 63) == 0) red[threadIdx.x >> 6] = s;
  __syncthreads();
  if (threadIdx.x == 0) {
    float t = 0.f;
    #pragma unroll
    for (int i = 0; i < 16; ++i) t += red[i];
    out[0] = t / (float)NROWS;
  }
}

extern "C" void kernel_launch(void* const* d_in, const int* in_sizes, int n_in,
                              void* d_out, int out_size, void* d_ws, size_t ws_size,
                              hipStream_t stream) {
  const float* x = (const float*)d_in[0];   // [4096,1024] fp32
  const float* w = (const float*)d_in[1];   // [50257,1024] fp32
  const int*   t = (const int*)d_in[2];     // [4096] int
  float* out = (float*)d_out;

  char* ws = (char*)d_ws;
  const size_t wq_bytes = (size_t)VPAD * DDIM;    // 51.5 MB fp8
  const size_t xq_bytes = (size_t)NROWS * DDIM;   //  4.2 MB fp8
  uint8_t* wq = (uint8_t*)ws;
  uint8_t* xq = (uint8_t*)(ws + wq_bytes);
  float*   S  = (float*)(ws + wq_bytes + xq_bytes);
  float*   lt = S + NROWS;

  if (ws_size < wq_bytes + xq_bytes + 2 * NROWS * sizeof(float)) return;

  hipMemsetAsync(S, 0, NROWS * sizeof(float), stream);
  cvtq_kernel<<<VPAD / 4, 256, 0, stream>>>(w, (uint32_t*)wq,
                                            (size_t)VDIM * DDIM, 64.0f);
  cvtq_kernel<<<NROWS / 4, 256, 0, stream>>>(x, (uint32_t*)xq,
                                             (size_t)NROWS * DDIM, 8.0f);
  tlogit_kernel<<<NROWS, 256, 0, stream>>>(x, w, t, lt);

  dim3 grid(NMT, NVT);  // (16, 393)
  gemm_lse_kernel<<<grid, 256, 0, stream>>>(xq, wq, S);

  loss_kernel<<<1, 1024, 0, stream>>>(S, lt, out);
}

// Round 4
// 664.581 us; speedup vs baseline: 1.0484x; 1.0484x over previous
//
#include <hip/hip_runtime.h>
#include <hip/hip_bf16.h>
#include <stdint.h>

// Problem constants (reference: N=4096, D=1024, V=50257)
#define NROWS 4096
#define DDIM  1024
#define VDIM  50257
#define VPAD  50304   // 393 * 128
#define NVT   393     // v-tiles
#define NMT   16      // m-tiles (256 rows each)

// fp8 scales: w*64, x*8 -> logits scaled by 512 (exact pow2, descale pre-exp)
#define DESCALE (1.0f / 512.0f)

typedef long  i64;
typedef i64   i64x2 __attribute__((ext_vector_type(2)));
typedef int   i32x4 __attribute__((ext_vector_type(4)));
typedef int   i32x8 __attribute__((ext_vector_type(8)));
typedef float f32x16 __attribute__((ext_vector_type(16)));

// e8m0 1.0 scales (exponent 127 -> 2^0): numerically exact, keeps absmax 0.
#define SCALE1 0x7F7F7F7F

// Fragment-ordered quantized layout (pre-swizzled in cvtq_frag):
//   frag (g, c) = 2 KB at byte ((g*16 + c)*64 + l)*32 + b,
//   holding src[g*32 + (l&31)][c*64 + (l>>5)*32 + b],  b = 0..31.
// This is exactly the 32x32x64 scaled-MFMA operand mapping (HW-verified
// rounds 1-3, absmax 0.0): lane l&31 = row/col index, l>>5 = k-half,
// 32 contiguous k-bytes per lane. A wave's fragment load is two fully
// coalesced global_load_dwordx4 (2 KB burst) -> no LDS, no barriers.
__device__ __forceinline__ i32x8 ld_gfrag(const uint8_t* p) {
  i32x4 lo = *(const i32x4*)p;
  i32x4 hi = *(const i32x4*)(p + 16);
  return __builtin_shufflevector(lo, hi, 0, 1, 2, 3, 4, 5, 6, 7);
}

// ---- fp32 -> fp8 e4m3, written in fragment order; zero pad rows ----
// One thread per (g, c, lane): t = (g*16 + c)*64 + l. Thread reads 32
// consecutive fp32 (128 B) of its (row, k-chunk) and writes 32 fp8 bytes
// contiguously; wave writes one full 2 KB fragment.
__global__ __launch_bounds__(256)
void cvtq_frag_kernel(const float* __restrict__ src, uint32_t* __restrict__ dst,
                      int nrows_valid, float scale) {
  int t = blockIdx.x * 256 + threadIdx.x;
  int l  = t & 63;
  int gc = t >> 6;                    // g*16 + c
  int row = (gc >> 4) * 32 + (l & 31);
  int col = (gc & 15) * 64 + (l >> 5) * 32;
  uint32_t o[8] = {0u,0u,0u,0u,0u,0u,0u,0u};
  if (row < nrows_valid) {
    const float4* s = (const float4*)(src + (size_t)row * DDIM + col);
    #pragma unroll
    for (int d = 0; d < 8; ++d) {
      float4 f = s[d];
      uint32_t v = 0;
      v = __builtin_amdgcn_cvt_pk_fp8_f32(f.x * scale, f.y * scale, v, false);
      v = __builtin_amdgcn_cvt_pk_fp8_f32(f.z * scale, f.w * scale, v, true);
      o[d] = v;
    }
  }
  uint4* dp = (uint4*)(dst + (size_t)t * 8);
  dp[0] = make_uint4(o[0], o[1], o[2], o[3]);
  dp[1] = make_uint4(o[4], o[5], o[6], o[7]);
}

// ---- exact fp32 target logit: lt[n] = dot(x[n], w[target[n]]) ----
__global__ __launch_bounds__(256)
void tlogit_kernel(const float* __restrict__ x, const float* __restrict__ w,
                   const int* __restrict__ tgt, float* __restrict__ lt) {
  int n = blockIdx.x;
  int t = tgt[n];
  const float4* xr = (const float4*)(x + (size_t)n * DDIM);
  const float4* wr = (const float4*)(w + (size_t)t * DDIM);
  float4 a = xr[threadIdx.x];
  float4 b = wr[threadIdx.x];
  float s = a.x * b.x + a.y * b.y + a.z * b.z + a.w * b.w;
  #pragma unroll
  for (int m = 32; m; m >>= 1) s += __shfl_down(s, m);
  __shared__ float red[4];
  if ((threadIdx.x & 63) == 0) red[threadIdx.x >> 6] = s;
  __syncthreads();
  if (threadIdx.x == 0) lt[n] = red[0] + red[1] + red[2] + red[3];
}

// ---- fused fp8 GEMM (scaled 32x32x64 f8f6f4, unit scales) + exp + row-sum ----
// LDS-FREE: block 256x128xBK64, 4 waves (2m x 2n), wave tile 128x64. Each
// wave loads its 6 operand fragments (4 A + 2 B) per k-iter directly from
// the fragment-ordered global tensors (coalesced 2 KB bursts, L2-resident)
// and issues 8 scaled MFMAs. No __syncthreads in the loop -> waves run
// free; VMEM latency hidden by 2 waves/SIMD + counted vmcnt. (Rounds 0-3
// showed the LDS-staged variant serializes LDS and MFMA phases in lockstep:
// MfmaUtil 20%, nothing saturated.)
// XCD swizzle: the 16 m-tiles of one v-slab share flat&7 -> one XCD streams
// each weight slab once; fragment A (4MB) is L2-resident per XCD.
__global__ __launch_bounds__(256, 2)
void gemm_lse_kernel(const uint8_t* __restrict__ xqf,  // frag-ordered fp8 x
                     const uint8_t* __restrict__ wqf,  // frag-ordered fp8 w
                     float* __restrict__ S) {          // [NROWS] sum of exp
  const int tid  = threadIdx.x;
  const int wid  = tid >> 6;    // 0..3
  const int lane = tid & 63;
  const int c31  = lane & 31;
  const int h    = lane >> 5;   // 0..1

  // Block remap: grid (16,393) -> flat; same-v blocks share flat&7 (same XCD
  // under id%8 round-robin). Tail 16 blocks -> v-tile 392.
  const int flat = blockIdx.x + blockIdx.y * 16;
  int bm, vt;
  if (flat >= (NVT - 1) * 16) { vt = NVT - 1; bm = flat - (NVT - 1) * 16; }
  else { vt = (flat >> 7) * 8 + (flat & 7); bm = (flat >> 3) & 15; }
  const int m0 = bm * 256;
  const int v0 = vt * 128;

  const int wave_m = wid >> 1;  // 0..1
  const int wave_n = wid & 1;   // 0..1

  // Fragment base pointers: frag (g, c) at (g*16 + c)*2048 + lane*32.
  const uint8_t* pA[4];
  #pragma unroll
  for (int mi = 0; mi < 4; ++mi)
    pA[mi] = xqf + ((size_t)(bm * 8 + wave_m * 4 + mi) * 16) * 2048 + lane * 32;
  const uint8_t* pB[2];
  #pragma unroll
  for (int ni = 0; ni < 2; ++ni)
    pB[ni] = wqf + ((size_t)(vt * 4 + wave_n * 2 + ni) * 16) * 2048 + lane * 32;

  f32x16 acc[4][2] = {};

  #pragma unroll 1   // keep regs tame: no cross-iter pipelining (r1 lesson)
  for (int c = 0; c < 16; ++c) {
    const size_t co = (size_t)c * 2048;
    i32x8 bf0 = ld_gfrag(pB[0] + co);
    i32x8 bf1 = ld_gfrag(pB[1] + co);
    #pragma unroll
    for (int mi = 0; mi < 4; ++mi) {
      i32x8 afm = ld_gfrag(pA[mi] + co);
      acc[mi][0] = __builtin_amdgcn_mfma_scale_f32_32x32x64_f8f6f4(
          afm, bf0, acc[mi][0], 0, 0, 0, SCALE1, 0, SCALE1);
      acc[mi][1] = __builtin_amdgcn_mfma_scale_f32_32x32x64_f8f6f4(
          afm, bf1, acc[mi][1], 0, 0, 0, SCALE1, 0, SCALE1);
    }
  }

  // Epilogue: descale, exp, row-sum. 32x32 C/D: col = lane&31,
  // row = (reg&3) + 8*(reg>>2) + 4*(lane>>5).
  #pragma unroll
  for (int mi = 0; mi < 4; ++mi) {
    #pragma unroll
    for (int r = 0; r < 16; ++r) {
      float pacc = 0.f;
      #pragma unroll
      for (int ni = 0; ni < 2; ++ni) {
        int v = v0 + wave_n * 64 + ni * 32 + c31;
        float e = __expf(acc[mi][ni][r] * DESCALE);
        pacc += (v < VDIM) ? e : 0.f;   // mask vocab pad
      }
      pacc += __shfl_xor(pacc, 16);
      pacc += __shfl_xor(pacc, 8);
      pacc += __shfl_xor(pacc, 4);
      pacc += __shfl_xor(pacc, 2);
      pacc += __shfl_xor(pacc, 1);
      if (c31 == 0) {
        int row = m0 + wave_m * 128 + mi * 32 + (r & 3) + 8 * (r >> 2) + 4 * h;
        atomicAdd(&S[row], pacc);
      }
    }
  }
}

// ---- final: loss = mean(log(S[n]) - lt[n]) ----
__global__ __launch_bounds__(1024)
void loss_kernel(const float* __restrict__ S, const float* __restrict__ lt,
                 float* __restrict__ out) {
  float s = 0.f;
  for (int n = threadIdx.x; n < NROWS; n += 1024)
    s += logf(S[n]) - lt[n];
  #pragma unroll
  for (int m = 32; m; m >>= 1) s += __shfl_down(s, m);
  __shared__ float red[16];
  if ((threadIdx.x & 63) == 0) red[threadIdx.x >> 6] = s;
  __syncthreads();
  if (threadIdx.x == 0) {
    float t = 0.f;
    #pragma unroll
    for (int i = 0; i < 16; ++i) t += red[i];
    out[0] = t / (float)NROWS;
  }
}

extern "C" void kernel_launch(void* const* d_in, const int* in_sizes, int n_in,
                              void* d_out, int out_size, void* d_ws, size_t ws_size,
                              hipStream_t stream) {
  const float* x = (const float*)d_in[0];   // [4096,1024] fp32
  const float* w = (const float*)d_in[1];   // [50257,1024] fp32
  const int*   t = (const int*)d_in[2];     // [4096] int
  float* out = (float*)d_out;

  char* ws = (char*)d_ws;
  const size_t wq_bytes = (size_t)VPAD * DDIM;    // 51.5 MB fp8 (frag order)
  const size_t xq_bytes = (size_t)NROWS * DDIM;   //  4.2 MB fp8 (frag order)
  uint8_t* wqf = (uint8_t*)ws;
  uint8_t* xqf = (uint8_t*)(ws + wq_bytes);
  float*   S   = (float*)(ws + wq_bytes + xq_bytes);
  float*   lt  = S + NROWS;

  if (ws_size < wq_bytes + xq_bytes + 2 * NROWS * sizeof(float)) return;

  hipMemsetAsync(S, 0, NROWS * sizeof(float), stream);
  // threads = rows*32 (one per (g,c,lane)); grid = rows*32/256 = rows/8
  cvtq_frag_kernel<<<VPAD / 8, 256, 0, stream>>>(w, (uint32_t*)wqf,
                                                 VDIM, 64.0f);
  cvtq_frag_kernel<<<NROWS / 8, 256, 0, stream>>>(x, (uint32_t*)xqf,
                                                  NROWS, 8.0f);
  tlogit_kernel<<<NROWS, 256, 0, stream>>>(x, w, t, lt);

  dim3 grid(NMT, NVT);  // (16, 393)
  gemm_lse_kernel<<<grid, 256, 0, stream>>>(xqf, wqf, S);

  loss_kernel<<<1, 1024, 0, stream>>>(S, lt, out);
}